// Round 7
// baseline (142.873 us; speedup 1.0000x reference)
//
#include <hip/hip_runtime.h>
#include <hip/hip_bf16.h>
#include <cstdint>

// Problem constants: B=2, N=2048, C=1024, H=16, D=64
// Q is stored pre-scaled by D^-0.5 * log2(e) so softmax runs in exp2 domain.
#define RMS_EPS 1.1920928955078125e-07f

typedef __bf16 bf16;
typedef __attribute__((ext_vector_type(8))) __bf16 bf16x8;
typedef __attribute__((ext_vector_type(4))) __bf16 bf16x4;
typedef __attribute__((ext_vector_type(4))) float f32x4;
typedef __attribute__((ext_vector_type(16))) float f32x16;
typedef unsigned int u32;
typedef __attribute__((ext_vector_type(4))) u32 u32x4;

__device__ __forceinline__ void gload16(const bf16* g, bf16* l) {
  __builtin_amdgcn_global_load_lds(
      (__attribute__((address_space(1))) void*)(g),
      (__attribute__((address_space(3))) void*)(l), 16, 0, 0);
}

__device__ __forceinline__ float fexp2(float x) {
#if __has_builtin(__builtin_amdgcn_exp2f)
  return __builtin_amdgcn_exp2f(x);
#else
  return exp2f(x);
#endif
}

__device__ __forceinline__ u32 pack2(float a, float b) {
  unsigned short xa = __builtin_bit_cast(unsigned short, (bf16)a);
  unsigned short xb = __builtin_bit_cast(unsigned short, (bf16)b);
  return (u32)xa | ((u32)xb << 16);
}

// ---------------- fused f32 -> bf16 convert for all three inputs ----------------
__global__ __launch_bounds__(256) void cvt3_kernel(
    const float* __restrict__ x, const float* __restrict__ wq, const float* __restrict__ wp,
    bf16* __restrict__ xo, bf16* __restrict__ wqo, bf16* __restrict__ wpo) {
  int i = blockIdx.x * 256 + threadIdx.x;
  const float* s; bf16* d; int off;
  if (i < 524288) { s = x; d = xo; off = i; }
  else if (i < 917504) { s = wq; d = wqo; off = i - 524288; }
  else { s = wp; d = wpo; off = i - 917504; }
  const float4* s4 = (const float4*)s;
  float4 a = s4[off * 2], b = s4[off * 2 + 1];
  bf16x8 o;
  o[0] = (bf16)a.x; o[1] = (bf16)a.y; o[2] = (bf16)a.z; o[3] = (bf16)a.w;
  o[4] = (bf16)b.x; o[5] = (bf16)b.y; o[6] = (bf16)b.z; o[7] = (bf16)b.w;
  *(bf16x8*)(d + off * 8) = o;
}

// ---------------- GEMM C = A * B^T, A:(M,1024) B:(Ncols,1024), both K-contig bf16
// T1: XCD-aware block swizzle (nwg % 8 == 0 for both instantiations -> bijective)
template <int MODE>
__global__ __launch_bounds__(256, 2) void gemm_bt(
    const bf16* __restrict__ A, const bf16* __restrict__ B,
    float* __restrict__ Cout, int Ncols,
    bf16* __restrict__ Qb, bf16* __restrict__ Kb, bf16* __restrict__ Vb,
    float* __restrict__ vninv) {
  __shared__ bf16 As[128 * 64];
  __shared__ bf16 Bs[128 * 64];
  const int tid = threadIdx.x;
  const int wave = tid >> 6, lane = tid & 63;
  const int l15 = lane & 15, g = lane >> 4;
  const int nwg = gridDim.x * gridDim.y;
  const int wg0 = blockIdx.y * gridDim.x + blockIdx.x;
  const int wg = (wg0 & 7) * (nwg >> 3) + (wg0 >> 3);
  const int m0 = (wg / gridDim.x) * 128, n0 = (wg % gridDim.x) * 128;
  const int wr = wave >> 1, wc = wave & 1;

  f32x4 acc[4][4] = {};

  for (int k0 = 0; k0 < 1024; k0 += 64) {
    __syncthreads();
#pragma unroll
    for (int i = 0; i < 4; ++i) {
      const int gid = (i * 4 + wave) * 64 + lane;
      const int row = gid >> 3, gk = gid & 7;
      const int srcoff = k0 + ((gk ^ (row & 7)) << 3);
      gload16(A + (m0 + row) * 1024 + srcoff, As + (i * 4 + wave) * 512);
      gload16(B + (n0 + row) * 1024 + srcoff, Bs + (i * 4 + wave) * 512);
    }
    __syncthreads();
#pragma unroll
    for (int kc = 0; kc < 2; ++kc) {
      bf16x8 af[4], bfb[4];
#pragma unroll
      for (int mi = 0; mi < 4; ++mi) {
        const int row = wr * 64 + mi * 16 + l15;
        af[mi] = *(const bf16x8*)&As[row * 64 + (((kc * 4 + g) ^ (l15 & 7)) << 3)];
      }
#pragma unroll
      for (int ni = 0; ni < 4; ++ni) {
        const int row = wc * 64 + ni * 16 + l15;
        bfb[ni] = *(const bf16x8*)&Bs[row * 64 + (((kc * 4 + g) ^ (l15 & 7)) << 3)];
      }
#pragma unroll
      for (int mi = 0; mi < 4; ++mi)
#pragma unroll
        for (int ni = 0; ni < 4; ++ni)
          acc[mi][ni] = __builtin_amdgcn_mfma_f32_16x16x32_bf16(af[mi], bfb[ni], acc[mi][ni], 0, 0, 0);
    }
  }

  if (MODE == 0) {
#pragma unroll
    for (int mi = 0; mi < 4; ++mi) {
      const int mrow = m0 + wr * 64 + mi * 16 + g * 4;
#pragma unroll
      for (int r = 0; r < 4; ++r) {
        float* cp = Cout + (long)(mrow + r) * Ncols + n0 + wc * 64 + l15;
#pragma unroll
        for (int ni = 0; ni < 4; ++ni) cp[ni * 16] = acc[mi][ni][r];
      }
    }
  } else {
    const int ncol = n0 + wc * 64;
    const int which = ncol >> 10;
    const int h = (ncol >> 6) & 15;
#pragma unroll
    for (int mi = 0; mi < 4; ++mi) {
#pragma unroll
      for (int r = 0; r < 4; ++r) {
        float ss = 0.f;
#pragma unroll
        for (int ni = 0; ni < 4; ++ni) ss += acc[mi][ni][r] * acc[mi][ni][r];
        ss += __shfl_xor(ss, 1); ss += __shfl_xor(ss, 2);
        ss += __shfl_xor(ss, 4); ss += __shfl_xor(ss, 8);
        const int m = m0 + wr * 64 + mi * 16 + g * 4 + r;
        const int b = m >> 11, nseq = m & 2047;
        const long base = ((long)(b * 16 + h) * 2048 + nseq) * 64 + l15;
        if (which == 0) {
          const float sc = rsqrtf(ss * (1.0f / 64) + RMS_EPS) * (0.125f * 1.44269504088896340736f);
#pragma unroll
          for (int ni = 0; ni < 4; ++ni) Qb[base + ni * 16] = (bf16)(acc[mi][ni][r] * sc);
        } else if (which == 1) {
          const float sc = rsqrtf(ss * (1.0f / 64) + RMS_EPS);
#pragma unroll
          for (int ni = 0; ni < 4; ++ni) Kb[base + ni * 16] = (bf16)(acc[mi][ni][r] * sc);
        } else {
#pragma unroll
          for (int ni = 0; ni < 4; ++ni) Vb[base + ni * 16] = (bf16)acc[mi][ni][r];
          if (l15 == 0) vninv[(b * 16 + h) * 2048 + nseq] = 1.0f / fmaxf(sqrtf(ss), 1e-12f);
        }
      }
    }
  }
}

// ---------------- flash attention, intra-block KV-split, 8 waves, 32x32 MFMA ----------------
// grid: 32 bh * 16 qblocks of 128 rows; 512 threads.
// Waves 0-3: KV rows [0,1024) ; waves 4-7: KV rows [1024,2048) — same 128 q-rows.
// Each half has its own double-buffered Ks/Vt (64KB LDS total) -> 2 blocks/CU = 4 waves/SIMD.
// End: split-1 publishes (m,l,O) via LDS; split-0 merges (online-softmax combine) + xsa epilogue.
struct ShMem {
  union {
    struct { bf16 Ks[2][2][4096]; bf16 Vt[2][2][4096]; } st;      // 64 KB staging
    struct { float Oex[4][64][32]; float2 mlex[4][64]; } mg;      // 34 KB merge exchange
  };
};

__global__ __launch_bounds__(512, 4) void attn_kernel(
    const bf16* __restrict__ Qb, const bf16* __restrict__ Kb, const bf16* __restrict__ Vb,
    const float* __restrict__ vninv, bf16* __restrict__ Yb) {
  __shared__ ShMem sh;

  const int tid = threadIdx.x;
  const int wq = tid >> 6;
  const int half = wq >> 2;        // KV split id
  const int wqh = wq & 3;          // wave within half
  const int tidh = tid & 255;      // thread within half
  const int lane = tid & 63;
  const int l31 = lane & 31, hi = lane >> 5;
  // XCD swizzle (512 blocks % 8 == 0 -> bijective): XCD k gets 4 bh complete.
  const int wg = (blockIdx.x & 7) * (gridDim.x >> 3) + (blockIdx.x >> 3);
  const int bh = wg >> 4, qb = wg & 15;
  const int b = bh >> 4, h = bh & 15;
  const long off = (long)bh * (2048 * 64);
  const bf16* Qp = Qb + off;
  const bf16* Kp = Kb + off;
  const bf16* Vp = Vb + off;
  const int qrow = qb * 128 + wqh * 32 + l31;
  const int kvbase = half * 1024;

  // Q B-frags in registers for the whole kernel: row q=l31, k = kc*16 + hi*8 + i
  bf16x8 qf[4];
#pragma unroll
  for (int kc = 0; kc < 4; ++kc)
    qf[kc] = *(const bf16x8*)&Qp[qrow * 64 + kc * 16 + hi * 8];

  f32x16 o[2] = {};  // O^T[d][q]: q = l31, d = (r&3)+8*(r>>2)+4*hi+32*dt
  float mrun = -__builtin_inff();
  float lrun = 0.f;

  // K staging geometry (per half: 4 waves stage one 64x64 tile, 2 gload16/thread)
  const int kj = lane >> 3, kgk = lane & 7;
  // prologue: stage this half's kv tile 0
#pragma unroll
  for (int i = 0; i < 2; ++i) {
    const int chunk = i * 4 + wqh;
    const int j = chunk * 8 + kj;
    gload16(Kp + (kvbase + j) * 64 + ((kgk ^ (j & 7)) << 3), &sh.st.Ks[half][0][chunk * 512]);
  }
#pragma unroll
  for (int i = 0; i < 2; ++i) {
    const int gid = i * 256 + tidh;
    const int j = gid >> 3, gk = gid & 7, jg = gid >> 6;
    bf16x8 v8 = *(const bf16x8*)&Vp[(kvbase + j) * 64 + gk * 8];
#pragma unroll
    for (int e = 0; e < 8; ++e)
      sh.st.Vt[half][0][(gk * 8 + e) * 64 + ((jg ^ gk ^ e) << 3) + (j & 7)] = v8[e];
  }
  __syncthreads();

  int cur = 0;
  for (int it = 0; it < 16; ++it) {
    const int kv0 = kvbase + it * 64;
    const bool pf = it < 15;
    bf16x8 v8[2];
    if (pf) {  // async-STAGE: issue next-tile loads early (T14)
#pragma unroll
      for (int i = 0; i < 2; ++i) {
        const int chunk = i * 4 + wqh;
        const int j = chunk * 8 + kj;
        gload16(Kp + (kv0 + 64 + j) * 64 + ((kgk ^ (j & 7)) << 3),
                &sh.st.Ks[half][cur ^ 1][chunk * 512]);
      }
#pragma unroll
      for (int i = 0; i < 2; ++i) {
        const int gid = i * 256 + tidh;
        v8[i] = *(const bf16x8*)&Vp[(kv0 + 64 + (gid >> 3)) * 64 + (gid & 7) * 8];
      }
    }
    const bf16* ks = &sh.st.Ks[half][cur][0];
    const bf16* vt = &sh.st.Vt[half][cur][0];

    // S^T = K * Q^T : lane holds S[j][q=l31], j = jt*32 + (r&3)+8*(r>>2)+4*hi
    f32x16 sv[2] = {};
    __builtin_amdgcn_s_setprio(1);
#pragma unroll
    for (int jt = 0; jt < 2; ++jt) {
      const int j = jt * 32 + l31;
#pragma unroll
      for (int kc = 0; kc < 4; ++kc) {
        bf16x8 kf = *(const bf16x8*)&ks[j * 64 + (((2 * kc + hi) ^ (j & 7)) << 3)];
        sv[jt] = __builtin_amdgcn_mfma_f32_32x32x16_bf16(kf, qf[kc], sv[jt], 0, 0, 0);
      }
    }
    __builtin_amdgcn_s_setprio(0);

    // ---- online softmax (exp2 domain), tree reductions, defer-max (T13) ----
    float mx[16];
#pragma unroll
    for (int r = 0; r < 16; ++r) mx[r] = fmaxf(sv[0][r], sv[1][r]);
#pragma unroll
    for (int s2 = 8; s2 > 0; s2 >>= 1)
#pragma unroll
      for (int r = 0; r < s2; ++r) mx[r] = fmaxf(mx[r], mx[r + s2]);
    float pmax = fmaxf(mx[0], __shfl_xor(mx[0], 32));

    if (!__all(pmax <= mrun + 8.f)) {  // rescale only when max grew past threshold
      const float mn = fmaxf(mrun, pmax);
      const float al = fexp2(mrun - mn);
      mrun = mn;
      lrun *= al;
#pragma unroll
      for (int dt = 0; dt < 2; ++dt)
#pragma unroll
        for (int r = 0; r < 16; ++r) o[dt][r] *= al;
    }

#pragma unroll
    for (int jt = 0; jt < 2; ++jt)
#pragma unroll
      for (int r = 0; r < 16; ++r) sv[jt][r] = fexp2(sv[jt][r] - mrun);
    float sm[16];
#pragma unroll
    for (int r = 0; r < 16; ++r) sm[r] = sv[0][r] + sv[1][r];
#pragma unroll
    for (int s2 = 8; s2 > 0; s2 >>= 1)
#pragma unroll
      for (int r = 0; r < s2; ++r) sm[r] += sm[r + s2];
    lrun += sm[0] + __shfl_xor(sm[0], 32);

    // ---- P (C-layout, q=lane) -> bf16 B-frags: pack + half-wave exchange ----
    u32 w[2][8], pw[2][8];
#pragma unroll
    for (int jt = 0; jt < 2; ++jt)
#pragma unroll
      for (int i = 0; i < 8; ++i) {
        w[jt][i] = pack2(sv[jt][2 * i], sv[jt][2 * i + 1]);
        pw[jt][i] = __shfl_xor(w[jt][i], 32);
      }
    bf16x8 pafr[4];  // B-frag kc: col q=l31, k-local i -> j = kc*16 + hi*8 + i
#pragma unroll
    for (int kc = 0; kc < 4; ++kc) {
      const int c = kc & 1, jt = kc >> 1;
      u32x4 pv;
      pv[0] = hi ? pw[jt][4 * c + 2] : w[jt][4 * c];
      pv[1] = hi ? pw[jt][4 * c + 3] : w[jt][4 * c + 1];
      pv[2] = hi ? w[jt][4 * c + 2] : pw[jt][4 * c];
      pv[3] = hi ? w[jt][4 * c + 3] : pw[jt][4 * c + 1];
      pafr[kc] = __builtin_bit_cast(bf16x8, pv);
    }

    // O^T += V^T * P : A = Vt rows (m=d), B = P (n=q)
    __builtin_amdgcn_s_setprio(1);
#pragma unroll
    for (int dt = 0; dt < 2; ++dt) {
      const int d = dt * 32 + l31;
      const int key = ((d >> 3) ^ d) & 7;
#pragma unroll
      for (int kc = 0; kc < 4; ++kc) {
        bf16x8 vf = *(const bf16x8*)&vt[d * 64 + (((2 * kc + hi) ^ key) << 3)];
        o[dt] = __builtin_amdgcn_mfma_f32_32x32x16_bf16(vf, pafr[kc], o[dt], 0, 0, 0);
      }
    }
    __builtin_amdgcn_s_setprio(0);

    if (pf) {  // late half of async-STAGE: write prefetched V into other buffer
#pragma unroll
      for (int i = 0; i < 2; ++i) {
        const int gid = i * 256 + tidh;
        const int j = gid >> 3, gk = gid & 7, jg = gid >> 6;
#pragma unroll
        for (int e = 0; e < 8; ++e)
          sh.st.Vt[half][cur ^ 1][(gk * 8 + e) * 64 + ((jg ^ gk ^ e) << 3) + (j & 7)] = v8[i][e];
      }
    }
    __syncthreads();
    cur ^= 1;
  }

  // ---- KV-split merge: split-1 publishes (m,l,O) via LDS, split-0 combines ----
  const int slot = wqh * 64 + lane;
  if (half == 1) {
    float4* dst = (float4*)&sh.mg.Oex[wqh][lane][0];
#pragma unroll
    for (int cchunk = 0; cchunk < 8; ++cchunk) {
      const int cs = cchunk ^ (slot & 7);  // bank-spread chunk swizzle
      float4 v;
      v.x = o[(cchunk * 4 + 0) >> 4][(cchunk * 4 + 0) & 15];
      v.y = o[(cchunk * 4 + 1) >> 4][(cchunk * 4 + 1) & 15];
      v.z = o[(cchunk * 4 + 2) >> 4][(cchunk * 4 + 2) & 15];
      v.w = o[(cchunk * 4 + 3) >> 4][(cchunk * 4 + 3) & 15];
      dst[cs] = v;
    }
    sh.mg.mlex[wqh][lane] = make_float2(mrun, lrun);
  }
  __syncthreads();
  if (half == 1) return;

  const float2 ml1 = sh.mg.mlex[wqh][lane];
  const float mtot = fmaxf(mrun, ml1.x);
  const float a0 = fexp2(mrun - mtot), a1 = fexp2(ml1.x - mtot);
  const float ltot = lrun * a0 + ml1.y * a1;
  {
    const float4* src = (const float4*)&sh.mg.Oex[wqh][lane][0];
#pragma unroll
    for (int cchunk = 0; cchunk < 8; ++cchunk) {
      const int cs = cchunk ^ (slot & 7);
      const float4 v = src[cs];
      o[(cchunk * 4 + 0) >> 4][(cchunk * 4 + 0) & 15] =
          o[(cchunk * 4 + 0) >> 4][(cchunk * 4 + 0) & 15] * a0 + v.x * a1;
      o[(cchunk * 4 + 1) >> 4][(cchunk * 4 + 1) & 15] =
          o[(cchunk * 4 + 1) >> 4][(cchunk * 4 + 1) & 15] * a0 + v.y * a1;
      o[(cchunk * 4 + 2) >> 4][(cchunk * 4 + 2) & 15] =
          o[(cchunk * 4 + 2) >> 4][(cchunk * 4 + 2) & 15] * a0 + v.z * a1;
      o[(cchunk * 4 + 3) >> 4][(cchunk * 4 + 3) & 15] =
          o[(cchunk * 4 + 3) >> 4][(cchunk * 4 + 3) & 15] * a0 + v.w * a1;
    }
  }

  // epilogue: y = O/l ; xsa: y -= (y . Vn) Vn ; store (B,N,C) bf16
  const float linv = 1.f / ltot;
  const float vni = vninv[bh * 2048 + qrow];
  const float cvn = vni * vni;
  float yv[2][16], vvf[2][16];
  float t = 0.f;
#pragma unroll
  for (int dt = 0; dt < 2; ++dt)
#pragma unroll
    for (int rr = 0; rr < 4; ++rr) {
      bf16x4 v4 = *(const bf16x4*)&Vp[qrow * 64 + dt * 32 + rr * 8 + hi * 4];
#pragma unroll
      for (int e = 0; e < 4; ++e) {
        const int r = rr * 4 + e;  // d = e + 8*rr + 4*hi + 32*dt
        const float y = o[dt][r] * linv;
        const float vx = (float)v4[e];
        yv[dt][r] = y; vvf[dt][r] = vx;
        t += y * vx;
      }
    }
  t += __shfl_xor(t, 32);
  const float coef = t * cvn;
  bf16* yp = Yb + ((long)b * 2048 + qrow) * 1024 + h * 64;
#pragma unroll
  for (int dt = 0; dt < 2; ++dt)
#pragma unroll
    for (int rr = 0; rr < 4; ++rr) {
      bf16x4 y4;
#pragma unroll
      for (int e = 0; e < 4; ++e) {
        const int r = rr * 4 + e;
        y4[e] = (bf16)(yv[dt][r] - coef * vvf[dt][r]);
      }
      *(bf16x4*)&yp[dt * 32 + rr * 8 + hi * 4] = y4;
    }
}

// ---------------- launch ----------------
extern "C" void kernel_launch(void* const* d_in, const int* in_sizes, int n_in,
                              void* d_out, int out_size, void* d_ws, size_t ws_size,
                              hipStream_t stream) {
  (void)in_sizes; (void)n_in; (void)out_size; (void)ws_size;
  const float* x = (const float*)d_in[0];
  const float* w_qkv = (const float*)d_in[1];
  const float* w_proj = (const float*)d_in[2];
  float* out = (float*)d_out;
  char* ws = (char*)d_ws;

  bf16* xb     = (bf16*)(ws);              //  8,388,608  x as bf16
  bf16* wqkvb  = (bf16*)(ws + 8388608);    //  6,291,456
  bf16* wprojb = (bf16*)(ws + 14680064);   //  2,097,152
  bf16* Qb     = (bf16*)(ws + 16777216);   //  8,388,608  (B,H,N,D) rms-normed * 0.125*log2e
  bf16* Kb     = (bf16*)(ws + 25165824);   //  8,388,608  (B,H,N,D) rms-normed
  bf16* Vb     = (bf16*)(ws + 33554432);   //  8,388,608  (B,H,N,D) raw
  float* vninv = (float*)(ws + 41943040);  //    524,288  1/max(||v||,1e-12)
  bf16* Yb     = (bf16*)(ws + 42467328);   //  8,388,608  (B,N,C) post-xsa

  cvt3_kernel<<<4096, 256, 0, stream>>>(x, w_qkv, w_proj, xb, wqkvb, wprojb);

  gemm_bt<1><<<dim3(24, 32), 256, 0, stream>>>(xb, wqkvb, nullptr, 3072,
                                               Qb, Kb, Vb, vninv);
  attn_kernel<<<512, 512, 0, stream>>>(Qb, Kb, Vb, vninv, Yb);
  gemm_bt<0><<<dim3(8, 32), 256, 0, stream>>>(Yb, wprojb, out, 1024,
                                              nullptr, nullptr, nullptr, nullptr);
}

// Round 8
// 142.340 us; speedup vs baseline: 1.0037x; 1.0037x over previous
//
#include <hip/hip_runtime.h>
#include <hip/hip_bf16.h>
#include <cstdint>

// Problem constants: B=2, N=2048, C=1024, H=16, D=64
// Q is stored pre-scaled by D^-0.5 * log2(e) so softmax runs in exp2 domain.
// V is materialized TRANSPOSED in global memory (VtG[bh][d][n]) by the QKV GEMM,
// so attention stages V^T with async global_load_lds like K (no in-kernel transpose).
#define RMS_EPS 1.1920928955078125e-07f

typedef __bf16 bf16;
typedef __attribute__((ext_vector_type(8))) __bf16 bf16x8;
typedef __attribute__((ext_vector_type(4))) __bf16 bf16x4;
typedef __attribute__((ext_vector_type(4))) float f32x4;
typedef __attribute__((ext_vector_type(16))) float f32x16;
typedef unsigned int u32;
typedef __attribute__((ext_vector_type(4))) u32 u32x4;

__device__ __forceinline__ void gload16(const bf16* g, bf16* l) {
  __builtin_amdgcn_global_load_lds(
      (__attribute__((address_space(1))) void*)(g),
      (__attribute__((address_space(3))) void*)(l), 16, 0, 0);
}

__device__ __forceinline__ float fexp2(float x) {
#if __has_builtin(__builtin_amdgcn_exp2f)
  return __builtin_amdgcn_exp2f(x);
#else
  return exp2f(x);
#endif
}

__device__ __forceinline__ u32 pack2(float a, float b) {
  unsigned short xa = __builtin_bit_cast(unsigned short, (bf16)a);
  unsigned short xb = __builtin_bit_cast(unsigned short, (bf16)b);
  return (u32)xa | ((u32)xb << 16);
}

// ---------------- fused f32 -> bf16 convert for all three inputs ----------------
__global__ __launch_bounds__(256) void cvt3_kernel(
    const float* __restrict__ x, const float* __restrict__ wq, const float* __restrict__ wp,
    bf16* __restrict__ xo, bf16* __restrict__ wqo, bf16* __restrict__ wpo) {
  int i = blockIdx.x * 256 + threadIdx.x;
  const float* s; bf16* d; int off;
  if (i < 524288) { s = x; d = xo; off = i; }
  else if (i < 917504) { s = wq; d = wqo; off = i - 524288; }
  else { s = wp; d = wpo; off = i - 917504; }
  const float4* s4 = (const float4*)s;
  float4 a = s4[off * 2], b = s4[off * 2 + 1];
  bf16x8 o;
  o[0] = (bf16)a.x; o[1] = (bf16)a.y; o[2] = (bf16)a.z; o[3] = (bf16)a.w;
  o[4] = (bf16)b.x; o[5] = (bf16)b.y; o[6] = (bf16)b.z; o[7] = (bf16)b.w;
  *(bf16x8*)(d + off * 8) = o;
}

// ---------------- GEMM C = A * B^T, A:(M,1024) B:(Ncols,1024), both K-contig bf16
// T1: XCD-aware block swizzle (nwg % 8 == 0 for both instantiations -> bijective)
// MODE 1 epilogue: rms_norm Q (x 0.125*log2e), rms_norm K, V stored TRANSPOSED (VtG[bh][d][n]).
template <int MODE>
__global__ __launch_bounds__(256, 2) void gemm_bt(
    const bf16* __restrict__ A, const bf16* __restrict__ B,
    float* __restrict__ Cout, int Ncols,
    bf16* __restrict__ Qb, bf16* __restrict__ Kb, bf16* __restrict__ VtG,
    float* __restrict__ vninv) {
  __shared__ bf16 As[128 * 64];
  __shared__ bf16 Bs[128 * 64];
  const int tid = threadIdx.x;
  const int wave = tid >> 6, lane = tid & 63;
  const int l15 = lane & 15, g = lane >> 4;
  const int nwg = gridDim.x * gridDim.y;
  const int wg0 = blockIdx.y * gridDim.x + blockIdx.x;
  const int wg = (wg0 & 7) * (nwg >> 3) + (wg0 >> 3);
  const int m0 = (wg / gridDim.x) * 128, n0 = (wg % gridDim.x) * 128;
  const int wr = wave >> 1, wc = wave & 1;

  f32x4 acc[4][4] = {};

  for (int k0 = 0; k0 < 1024; k0 += 64) {
    __syncthreads();
#pragma unroll
    for (int i = 0; i < 4; ++i) {
      const int gid = (i * 4 + wave) * 64 + lane;
      const int row = gid >> 3, gk = gid & 7;
      const int srcoff = k0 + ((gk ^ (row & 7)) << 3);
      gload16(A + (m0 + row) * 1024 + srcoff, As + (i * 4 + wave) * 512);
      gload16(B + (n0 + row) * 1024 + srcoff, Bs + (i * 4 + wave) * 512);
    }
    __syncthreads();
#pragma unroll
    for (int kc = 0; kc < 2; ++kc) {
      bf16x8 af[4], bfb[4];
#pragma unroll
      for (int mi = 0; mi < 4; ++mi) {
        const int row = wr * 64 + mi * 16 + l15;
        af[mi] = *(const bf16x8*)&As[row * 64 + (((kc * 4 + g) ^ (l15 & 7)) << 3)];
      }
#pragma unroll
      for (int ni = 0; ni < 4; ++ni) {
        const int row = wc * 64 + ni * 16 + l15;
        bfb[ni] = *(const bf16x8*)&Bs[row * 64 + (((kc * 4 + g) ^ (l15 & 7)) << 3)];
      }
#pragma unroll
      for (int mi = 0; mi < 4; ++mi)
#pragma unroll
        for (int ni = 0; ni < 4; ++ni)
          acc[mi][ni] = __builtin_amdgcn_mfma_f32_16x16x32_bf16(af[mi], bfb[ni], acc[mi][ni], 0, 0, 0);
    }
  }

  if (MODE == 0) {
#pragma unroll
    for (int mi = 0; mi < 4; ++mi) {
      const int mrow = m0 + wr * 64 + mi * 16 + g * 4;
#pragma unroll
      for (int r = 0; r < 4; ++r) {
        float* cp = Cout + (long)(mrow + r) * Ncols + n0 + wc * 64 + l15;
#pragma unroll
        for (int ni = 0; ni < 4; ++ni) cp[ni * 16] = acc[mi][ni][r];
      }
    }
  } else {
    const int ncol = n0 + wc * 64;
    const int which = ncol >> 10;
    const int h = (ncol >> 6) & 15;
#pragma unroll
    for (int mi = 0; mi < 4; ++mi) {
#pragma unroll
      for (int r = 0; r < 4; ++r) {
        float ss = 0.f;
#pragma unroll
        for (int ni = 0; ni < 4; ++ni) ss += acc[mi][ni][r] * acc[mi][ni][r];
        ss += __shfl_xor(ss, 1); ss += __shfl_xor(ss, 2);
        ss += __shfl_xor(ss, 4); ss += __shfl_xor(ss, 8);
        const int m = m0 + wr * 64 + mi * 16 + g * 4 + r;
        const int b = m >> 11, nseq = m & 2047;
        const int bh = b * 16 + h;
        const long base = ((long)bh * 2048 + nseq) * 64 + l15;
        if (which == 0) {
          const float sc = rsqrtf(ss * (1.0f / 64) + RMS_EPS) * (0.125f * 1.44269504088896340736f);
#pragma unroll
          for (int ni = 0; ni < 4; ++ni) Qb[base + ni * 16] = (bf16)(acc[mi][ni][r] * sc);
        } else if (which == 1) {
          const float sc = rsqrtf(ss * (1.0f / 64) + RMS_EPS);
#pragma unroll
          for (int ni = 0; ni < 4; ++ni) Kb[base + ni * 16] = (bf16)(acc[mi][ni][r] * sc);
        } else {
          // V transposed: VtG[bh*64 + d][nseq], d = ni*16 + l15
          const long vbase = (long)bh * 64 * 2048 + nseq;
#pragma unroll
          for (int ni = 0; ni < 4; ++ni)
            VtG[vbase + (long)(ni * 16 + l15) * 2048] = (bf16)acc[mi][ni][r];
          if (l15 == 0) vninv[bh * 2048 + nseq] = 1.0f / fmaxf(sqrtf(ss), 1e-12f);
        }
      }
    }
  }
}

// ---------------- flash attention, 4 warps x 32x32 MFMA, swapped operands ----------------
// grid: 32 bh * 16 qblocks of 128 rows; 256 threads; warp owns 32 q-rows.
// T1 XCD swizzle; K and V^T both staged via async gload16 with source-granule XOR swizzle.
__global__ __launch_bounds__(256, 2) void attn_kernel(
    const bf16* __restrict__ Qb, const bf16* __restrict__ Kb, const bf16* __restrict__ VtG,
    const float* __restrict__ vninv, bf16* __restrict__ Yb) {
  __shared__ bf16 Ks[2][64 * 64];  // [j][d] linear, source-granule-swizzled by (j&7)
  __shared__ bf16 Vt[2][64 * 64];  // [d][j] linear (V^T rows), source-granule-swizzled by (d&7)

  const int tid = threadIdx.x;
  const int wq = tid >> 6;
  const int lane = tid & 63;
  const int l31 = lane & 31, hi = lane >> 5;
  // XCD swizzle (512 blocks % 8 == 0 -> bijective): XCD k gets 4 bh complete.
  const int wg = (blockIdx.x & 7) * (gridDim.x >> 3) + (blockIdx.x >> 3);
  const int bh = wg >> 4, qb = wg & 15;
  const int b = bh >> 4, h = bh & 15;
  const long off = (long)bh * (2048 * 64);
  const bf16* Qp = Qb + off;
  const bf16* Kp = Kb + off;
  const bf16* VtP = VtG + (long)bh * 64 * 2048;
  const int qrow = qb * 128 + wq * 32 + l31;

  // Q B-frags in registers for the whole kernel: row q=l31, k = kc*16 + hi*8 + i
  bf16x8 qf[4];
#pragma unroll
  for (int kc = 0; kc < 4; ++kc)
    qf[kc] = *(const bf16x8*)&Qp[qrow * 64 + kc * 16 + hi * 8];

  f32x16 o[2] = {};  // O^T[d][q]: q = l31, d = (r&3)+8*(r>>2)+4*hi+32*dt
  float mrun = -__builtin_inff();
  float lrun = 0.f;

  // staging geometry: granule gid = chunk*64 + lane; row = gid>>3 = chunk*8 + (lane>>3);
  // gran k = lane&7; source granule XOR-swizzled by (row&7); LDS linear at gid*8 elems.
  const int kj = lane >> 3, kgk = lane & 7;
  int koff[2], voff[2];
#pragma unroll
  for (int i = 0; i < 2; ++i) {
    const int chunk = i * 4 + wq;
    const int row = chunk * 8 + kj;
    const int sw = (kgk ^ (row & 7)) << 3;
    koff[i] = row * 64 + sw;    // K: row j, + kv0*64 per tile
    voff[i] = row * 2048 + sw;  // V^T: row d (stride 2048), + kv0 per tile
  }

  // prologue: stage kv tile 0
#pragma unroll
  for (int i = 0; i < 2; ++i) {
    const int chunk = i * 4 + wq;
    gload16(Kp + koff[i], &Ks[0][chunk * 512]);
    gload16(VtP + voff[i], &Vt[0][chunk * 512]);
  }
  __syncthreads();

  int cur = 0;
  for (int kv0 = 0; kv0 < 2048; kv0 += 64) {
    if (kv0 + 64 < 2048) {  // async prefetch next tile (T14): pure gload16
#pragma unroll
      for (int i = 0; i < 2; ++i) {
        const int chunk = i * 4 + wq;
        gload16(Kp + (kv0 + 64) * 64 + koff[i], &Ks[cur ^ 1][chunk * 512]);
        gload16(VtP + (kv0 + 64) + voff[i], &Vt[cur ^ 1][chunk * 512]);
      }
    }
    const bf16* ks = &Ks[cur][0];
    const bf16* vt = &Vt[cur][0];

    // S^T = K * Q^T : lane holds S[j][q=l31], j = jt*32 + (r&3)+8*(r>>2)+4*hi
    f32x16 sv[2] = {};
    __builtin_amdgcn_s_setprio(1);
#pragma unroll
    for (int jt = 0; jt < 2; ++jt) {
      const int j = jt * 32 + l31;
#pragma unroll
      for (int kc = 0; kc < 4; ++kc) {
        bf16x8 kf = *(const bf16x8*)&ks[j * 64 + (((2 * kc + hi) ^ (j & 7)) << 3)];
        sv[jt] = __builtin_amdgcn_mfma_f32_32x32x16_bf16(kf, qf[kc], sv[jt], 0, 0, 0);
      }
    }
    __builtin_amdgcn_s_setprio(0);

    // ---- online softmax (exp2 domain), tree reductions, defer-max (T13) ----
    float mx[16];
#pragma unroll
    for (int r = 0; r < 16; ++r) mx[r] = fmaxf(sv[0][r], sv[1][r]);
#pragma unroll
    for (int s2 = 8; s2 > 0; s2 >>= 1)
#pragma unroll
      for (int r = 0; r < s2; ++r) mx[r] = fmaxf(mx[r], mx[r + s2]);
    float pmax = fmaxf(mx[0], __shfl_xor(mx[0], 32));

    if (!__all(pmax <= mrun + 8.f)) {  // rescale only when max grew past threshold
      const float mn = fmaxf(mrun, pmax);
      const float al = fexp2(mrun - mn);
      mrun = mn;
      lrun *= al;
#pragma unroll
      for (int dt = 0; dt < 2; ++dt)
#pragma unroll
        for (int r = 0; r < 16; ++r) o[dt][r] *= al;
    }

#pragma unroll
    for (int jt = 0; jt < 2; ++jt)
#pragma unroll
      for (int r = 0; r < 16; ++r) sv[jt][r] = fexp2(sv[jt][r] - mrun);
    float sm[16];
#pragma unroll
    for (int r = 0; r < 16; ++r) sm[r] = sv[0][r] + sv[1][r];
#pragma unroll
    for (int s2 = 8; s2 > 0; s2 >>= 1)
#pragma unroll
      for (int r = 0; r < s2; ++r) sm[r] += sm[r + s2];
    lrun += sm[0] + __shfl_xor(sm[0], 32);

    // ---- P (C-layout, q=lane) -> bf16 B-frags: pack + half-wave exchange ----
    u32 w[2][8], pw[2][8];
#pragma unroll
    for (int jt = 0; jt < 2; ++jt)
#pragma unroll
      for (int i = 0; i < 8; ++i) {
        w[jt][i] = pack2(sv[jt][2 * i], sv[jt][2 * i + 1]);
        pw[jt][i] = __shfl_xor(w[jt][i], 32);
      }
    bf16x8 pafr[4];  // B-frag kc: col q=l31, k-local i -> j = kc*16 + hi*8 + i
#pragma unroll
    for (int kc = 0; kc < 4; ++kc) {
      const int c = kc & 1, jt = kc >> 1;
      u32x4 pv;
      pv[0] = hi ? pw[jt][4 * c + 2] : w[jt][4 * c];
      pv[1] = hi ? pw[jt][4 * c + 3] : w[jt][4 * c + 1];
      pv[2] = hi ? w[jt][4 * c + 2] : pw[jt][4 * c];
      pv[3] = hi ? w[jt][4 * c + 3] : pw[jt][4 * c + 1];
      pafr[kc] = __builtin_bit_cast(bf16x8, pv);
    }

    // O^T += V^T * P : A = Vt rows (m=d, swizzle key d&7 = l31&7), B = P (n=q)
    __builtin_amdgcn_s_setprio(1);
#pragma unroll
    for (int dt = 0; dt < 2; ++dt) {
      const int d = dt * 32 + l31;
#pragma unroll
      for (int kc = 0; kc < 4; ++kc) {
        bf16x8 vf = *(const bf16x8*)&vt[d * 64 + (((2 * kc + hi) ^ (l31 & 7)) << 3)];
        o[dt] = __builtin_amdgcn_mfma_f32_32x32x16_bf16(vf, pafr[kc], o[dt], 0, 0, 0);
      }
    }
    __builtin_amdgcn_s_setprio(0);

    __syncthreads();
    cur ^= 1;
  }

  // epilogue: y = O/l ; xsa: y -= (y . Vn) Vn ; store (B,N,C) bf16
  // V rows read from V^T columns: VtP[d*2048 + qrow] (coalesced across lanes).
  const float linv = 1.f / lrun;
  const float vni = vninv[bh * 2048 + qrow];
  const float cvn = vni * vni;
  const bf16* vq = VtP + qrow;
  float yv[2][16], vvf[2][16];
  float t = 0.f;
#pragma unroll
  for (int dt = 0; dt < 2; ++dt)
#pragma unroll
    for (int rr = 0; rr < 4; ++rr) {
#pragma unroll
      for (int e = 0; e < 4; ++e) {
        const int r = rr * 4 + e;  // d = e + 8*rr + 4*hi + 32*dt
        const int d = e + 8 * rr + 4 * hi + 32 * dt;
        const float y = o[dt][r] * linv;
        const float vx = (float)vq[d * 2048];
        yv[dt][r] = y; vvf[dt][r] = vx;
        t += y * vx;
      }
    }
  t += __shfl_xor(t, 32);
  const float coef = t * cvn;
  bf16* yp = Yb + ((long)b * 2048 + qrow) * 1024 + h * 64;
#pragma unroll
  for (int dt = 0; dt < 2; ++dt)
#pragma unroll
    for (int rr = 0; rr < 4; ++rr) {
      bf16x4 y4;
#pragma unroll
      for (int e = 0; e < 4; ++e) {
        const int r = rr * 4 + e;
        y4[e] = (bf16)(yv[dt][r] - coef * vvf[dt][r]);
      }
      *(bf16x4*)&yp[dt * 32 + rr * 8 + hi * 4] = y4;
    }
}

// ---------------- launch ----------------
extern "C" void kernel_launch(void* const* d_in, const int* in_sizes, int n_in,
                              void* d_out, int out_size, void* d_ws, size_t ws_size,
                              hipStream_t stream) {
  (void)in_sizes; (void)n_in; (void)out_size; (void)ws_size;
  const float* x = (const float*)d_in[0];
  const float* w_qkv = (const float*)d_in[1];
  const float* w_proj = (const float*)d_in[2];
  float* out = (float*)d_out;
  char* ws = (char*)d_ws;

  bf16* xb     = (bf16*)(ws);              //  8,388,608  x as bf16
  bf16* wqkvb  = (bf16*)(ws + 8388608);    //  6,291,456
  bf16* wprojb = (bf16*)(ws + 14680064);   //  2,097,152
  bf16* Qb     = (bf16*)(ws + 16777216);   //  8,388,608  (B,H,N,D) rms-normed * 0.125*log2e
  bf16* Kb     = (bf16*)(ws + 25165824);   //  8,388,608  (B,H,N,D) rms-normed
  bf16* VtG    = (bf16*)(ws + 33554432);   //  8,388,608  (B,H,D,N) V transposed
  float* vninv = (float*)(ws + 41943040);  //    524,288  1/max(||v||,1e-12)
  bf16* Yb     = (bf16*)(ws + 42467328);   //  8,388,608  (B,N,C) post-xsa

  cvt3_kernel<<<4096, 256, 0, stream>>>(x, w_qkv, w_proj, xb, wqkvb, wprojb);

  gemm_bt<1><<<dim3(24, 32), 256, 0, stream>>>(xb, wqkvb, nullptr, 3072,
                                               Qb, Kb, VtG, vninv);
  attn_kernel<<<512, 256, 0, stream>>>(Qb, Kb, VtG, vninv, Yb);
  gemm_bt<0><<<dim3(8, 32), 256, 0, stream>>>(Yb, wprojb, out, 1024,
                                              nullptr, nullptr, nullptr, nullptr);
}

// Round 9
// 133.765 us; speedup vs baseline: 1.0681x; 1.0641x over previous
//
#include <hip/hip_runtime.h>
#include <hip/hip_bf16.h>
#include <cstdint>

// Problem constants: B=2, N=2048, C=1024, H=16, D=64
// Q is stored pre-scaled by D^-0.5 * log2(e) so softmax runs in exp2 domain.
// V is materialized TRANSPOSED in global memory (VtG[bh][d][n]) by the QKV GEMM.
#define RMS_EPS 1.1920928955078125e-07f

typedef __bf16 bf16;
typedef __attribute__((ext_vector_type(8))) __bf16 bf16x8;
typedef __attribute__((ext_vector_type(4))) __bf16 bf16x4;
typedef __attribute__((ext_vector_type(4))) float f32x4;
typedef __attribute__((ext_vector_type(16))) float f32x16;
typedef unsigned int u32;
typedef __attribute__((ext_vector_type(4))) u32 u32x4;

__device__ __forceinline__ void gload16(const bf16* g, bf16* l) {
  __builtin_amdgcn_global_load_lds(
      (__attribute__((address_space(1))) void*)(g),
      (__attribute__((address_space(3))) void*)(l), 16, 0, 0);
}

__device__ __forceinline__ float fexp2(float x) {
#if __has_builtin(__builtin_amdgcn_exp2f)
  return __builtin_amdgcn_exp2f(x);
#else
  return exp2f(x);
#endif
}

__device__ __forceinline__ u32 pack2(float a, float b) {
  unsigned short xa = __builtin_bit_cast(unsigned short, (bf16)a);
  unsigned short xb = __builtin_bit_cast(unsigned short, (bf16)b);
  return (u32)xa | ((u32)xb << 16);
}

// ---------------- fused f32 -> bf16 convert for all three inputs ----------------
__global__ __launch_bounds__(256) void cvt3_kernel(
    const float* __restrict__ x, const float* __restrict__ wq, const float* __restrict__ wp,
    bf16* __restrict__ xo, bf16* __restrict__ wqo, bf16* __restrict__ wpo) {
  int i = blockIdx.x * 256 + threadIdx.x;
  const float* s; bf16* d; int off;
  if (i < 524288) { s = x; d = xo; off = i; }
  else if (i < 917504) { s = wq; d = wqo; off = i - 524288; }
  else { s = wp; d = wpo; off = i - 917504; }
  const float4* s4 = (const float4*)s;
  float4 a = s4[off * 2], b = s4[off * 2 + 1];
  bf16x8 o;
  o[0] = (bf16)a.x; o[1] = (bf16)a.y; o[2] = (bf16)a.z; o[3] = (bf16)a.w;
  o[4] = (bf16)b.x; o[5] = (bf16)b.y; o[6] = (bf16)b.z; o[7] = (bf16)b.w;
  *(bf16x8*)(d + off * 8) = o;
}

// ---------------- GEMM C = A * B^T, A:(M,1024) B:(Ncols,1024), both K-contig bf16
// T1: XCD-aware block swizzle. MODE 1 epilogue: rms_norm Q (x0.125*log2e), rms_norm K,
// V stored TRANSPOSED (VtG[bh][d][n]) + vninv.
template <int MODE>
__global__ __launch_bounds__(256, 2) void gemm_bt(
    const bf16* __restrict__ A, const bf16* __restrict__ B,
    float* __restrict__ Cout, int Ncols,
    bf16* __restrict__ Qb, bf16* __restrict__ Kb, bf16* __restrict__ VtG,
    float* __restrict__ vninv) {
  __shared__ bf16 As[128 * 64];
  __shared__ bf16 Bs[128 * 64];
  const int tid = threadIdx.x;
  const int wave = tid >> 6, lane = tid & 63;
  const int l15 = lane & 15, g = lane >> 4;
  const int nwg = gridDim.x * gridDim.y;
  const int wg0 = blockIdx.y * gridDim.x + blockIdx.x;
  const int wg = (wg0 & 7) * (nwg >> 3) + (wg0 >> 3);
  const int m0 = (wg / gridDim.x) * 128, n0 = (wg % gridDim.x) * 128;
  const int wr = wave >> 1, wc = wave & 1;

  f32x4 acc[4][4] = {};

  for (int k0 = 0; k0 < 1024; k0 += 64) {
    __syncthreads();
#pragma unroll
    for (int i = 0; i < 4; ++i) {
      const int gid = (i * 4 + wave) * 64 + lane;
      const int row = gid >> 3, gk = gid & 7;
      const int srcoff = k0 + ((gk ^ (row & 7)) << 3);
      gload16(A + (m0 + row) * 1024 + srcoff, As + (i * 4 + wave) * 512);
      gload16(B + (n0 + row) * 1024 + srcoff, Bs + (i * 4 + wave) * 512);
    }
    __syncthreads();
#pragma unroll
    for (int kc = 0; kc < 2; ++kc) {
      bf16x8 af[4], bfb[4];
#pragma unroll
      for (int mi = 0; mi < 4; ++mi) {
        const int row = wr * 64 + mi * 16 + l15;
        af[mi] = *(const bf16x8*)&As[row * 64 + (((kc * 4 + g) ^ (l15 & 7)) << 3)];
      }
#pragma unroll
      for (int ni = 0; ni < 4; ++ni) {
        const int row = wc * 64 + ni * 16 + l15;
        bfb[ni] = *(const bf16x8*)&Bs[row * 64 + (((kc * 4 + g) ^ (l15 & 7)) << 3)];
      }
#pragma unroll
      for (int mi = 0; mi < 4; ++mi)
#pragma unroll
        for (int ni = 0; ni < 4; ++ni)
          acc[mi][ni] = __builtin_amdgcn_mfma_f32_16x16x32_bf16(af[mi], bfb[ni], acc[mi][ni], 0, 0, 0);
    }
  }

  if (MODE == 0) {
#pragma unroll
    for (int mi = 0; mi < 4; ++mi) {
      const int mrow = m0 + wr * 64 + mi * 16 + g * 4;
#pragma unroll
      for (int r = 0; r < 4; ++r) {
        float* cp = Cout + (long)(mrow + r) * Ncols + n0 + wc * 64 + l15;
#pragma unroll
        for (int ni = 0; ni < 4; ++ni) cp[ni * 16] = acc[mi][ni][r];
      }
    }
  } else {
    const int ncol = n0 + wc * 64;
    const int which = ncol >> 10;
    const int h = (ncol >> 6) & 15;
#pragma unroll
    for (int mi = 0; mi < 4; ++mi) {
#pragma unroll
      for (int r = 0; r < 4; ++r) {
        float ss = 0.f;
#pragma unroll
        for (int ni = 0; ni < 4; ++ni) ss += acc[mi][ni][r] * acc[mi][ni][r];
        ss += __shfl_xor(ss, 1); ss += __shfl_xor(ss, 2);
        ss += __shfl_xor(ss, 4); ss += __shfl_xor(ss, 8);
        const int m = m0 + wr * 64 + mi * 16 + g * 4 + r;
        const int b = m >> 11, nseq = m & 2047;
        const int bh = b * 16 + h;
        const long base = ((long)bh * 2048 + nseq) * 64 + l15;
        if (which == 0) {
          const float sc = rsqrtf(ss * (1.0f / 64) + RMS_EPS) * (0.125f * 1.44269504088896340736f);
#pragma unroll
          for (int ni = 0; ni < 4; ++ni) Qb[base + ni * 16] = (bf16)(acc[mi][ni][r] * sc);
        } else if (which == 1) {
          const float sc = rsqrtf(ss * (1.0f / 64) + RMS_EPS);
#pragma unroll
          for (int ni = 0; ni < 4; ++ni) Kb[base + ni * 16] = (bf16)(acc[mi][ni][r] * sc);
        } else {
          const long vbase = (long)bh * 64 * 2048 + nseq;
#pragma unroll
          for (int ni = 0; ni < 4; ++ni)
            VtG[vbase + (long)(ni * 16 + l15) * 2048] = (bf16)acc[mi][ni][r];
          if (l15 == 0) vninv[bh * 2048 + nseq] = 1.0f / fmaxf(sqrtf(ss), 1e-12f);
        }
      }
    }
  }
}

// ---------------- flash attention, 4 warps x 32x32 MFMA, swapped operands, KVBLK=128 ----
// grid: 32 bh * 16 qblocks of 128 rows; 256 threads; warp owns 32 q-rows.
// 16 fat iterations of 128 KV rows (4 j-tiles); halves all per-iter fixed costs.
// K and V^T staged via async gload16; conflict-free XOR key (row ^ (row>>3)) & 7 on
// BOTH stage-source and read side (self-consistent bijection).
__global__ __launch_bounds__(256, 2) void attn_kernel(
    const bf16* __restrict__ Qb, const bf16* __restrict__ Kb, const bf16* __restrict__ VtG,
    const float* __restrict__ vninv, bf16* __restrict__ Yb) {
  __shared__ bf16 Ks[2][128 * 64];  // [j][d] linear, 16 KB per buffer
  __shared__ bf16 Vt[2][64 * 128];  // [d][j] linear (V^T rows), 16 KB per buffer

  const int tid = threadIdx.x;
  const int wq = tid >> 6;
  const int lane = tid & 63;
  const int l31 = lane & 31, hi = lane >> 5;
  // XCD swizzle (512 blocks % 8 == 0 -> bijective)
  const int wg = (blockIdx.x & 7) * (gridDim.x >> 3) + (blockIdx.x >> 3);
  const int bh = wg >> 4, qb = wg & 15;
  const int b = bh >> 4, h = bh & 15;
  const long off = (long)bh * (2048 * 64);
  const bf16* Qp = Qb + off;
  const bf16* Kp = Kb + off;
  const bf16* VtP = VtG + (long)bh * 64 * 2048;
  const int qrow = qb * 128 + wq * 32 + l31;

  // Q B-frags in registers: row q=l31, k = kc*16 + hi*8 + i
  bf16x8 qf[4];
#pragma unroll
  for (int kc = 0; kc < 4; ++kc)
    qf[kc] = *(const bf16x8*)&Qp[qrow * 64 + kc * 16 + hi * 8];

  f32x16 o[2] = {};  // O^T[d][q]: q=l31, d = (r&3)+8*(r>>2)+4*hi+32*dt
  float mrun = -__builtin_inff();
  float lrun = 0.f;

  // ---- staging offsets (4 granules each for K and Vt per thread) ----
  // K: chunk = i*4+wq (16 chunks of 64 granules); row j = chunk*8 + (lane>>3); gk = lane&7.
  // Vt: same chunks; row d = chunk*4 + (lane>>4); c16 = lane&15 (16 granules per 128-elem row).
  int koff[4], voff[4];
#pragma unroll
  for (int i = 0; i < 4; ++i) {
    const int chunk = i * 4 + wq;
    const int j = chunk * 8 + (lane >> 3);
    koff[i] = j * 64 + (((lane & 7) ^ ((j ^ (j >> 3)) & 7)) << 3);
    const int d = chunk * 4 + (lane >> 4);
    voff[i] = d * 2048 + (((lane & 15) ^ ((d ^ (d >> 3)) & 7)) << 3);
  }

  // prologue: stage kv tile 0
#pragma unroll
  for (int i = 0; i < 4; ++i) {
    const int chunk = i * 4 + wq;
    gload16(Kp + koff[i], &Ks[0][chunk * 512]);
    gload16(VtP + voff[i], &Vt[0][chunk * 512]);
  }
  __syncthreads();

  int cur = 0;
  for (int it = 0; it < 16; ++it) {
    const int kv0 = it * 128;
    if (it < 15) {  // async prefetch next fat tile (T14)
#pragma unroll
      for (int i = 0; i < 4; ++i) {
        const int chunk = i * 4 + wq;
        gload16(Kp + (kv0 + 128) * 64 + koff[i], &Ks[cur ^ 1][chunk * 512]);
        gload16(VtP + (kv0 + 128) + voff[i], &Vt[cur ^ 1][chunk * 512]);
      }
    }
    const bf16* ks = &Ks[cur][0];
    const bf16* vt = &Vt[cur][0];

    // S^T = K * Q^T : sv[jt], lane holds S[j][q=l31], j = jt*32 + (r&3)+8*(r>>2)+4*hi
    f32x16 sv[4] = {};
    __builtin_amdgcn_s_setprio(1);
#pragma unroll
    for (int jt = 0; jt < 4; ++jt) {
      const int j = jt * 32 + l31;
      const int key = (j ^ (j >> 3)) & 7;
#pragma unroll
      for (int kc = 0; kc < 4; ++kc) {
        bf16x8 kf = *(const bf16x8*)&ks[j * 64 + (((2 * kc + hi) ^ key) << 3)];
        sv[jt] = __builtin_amdgcn_mfma_f32_32x32x16_bf16(kf, qf[kc], sv[jt], 0, 0, 0);
      }
    }
    __builtin_amdgcn_s_setprio(0);

    // ---- online softmax (exp2 domain), tree reductions, defer-max (T13) ----
    float mx[16];
#pragma unroll
    for (int r = 0; r < 16; ++r)
      mx[r] = fmaxf(fmaxf(sv[0][r], sv[1][r]), fmaxf(sv[2][r], sv[3][r]));
#pragma unroll
    for (int s2 = 8; s2 > 0; s2 >>= 1)
#pragma unroll
      for (int r = 0; r < s2; ++r) mx[r] = fmaxf(mx[r], mx[r + s2]);
    float pmax = fmaxf(mx[0], __shfl_xor(mx[0], 32));

    if (!__all(pmax <= mrun + 8.f)) {  // rescale only when max grew past threshold
      const float mn = fmaxf(mrun, pmax);
      const float al = fexp2(mrun - mn);
      mrun = mn;
      lrun *= al;
#pragma unroll
      for (int dt = 0; dt < 2; ++dt)
#pragma unroll
        for (int r = 0; r < 16; ++r) o[dt][r] *= al;
    }

#pragma unroll
    for (int jt = 0; jt < 4; ++jt)
#pragma unroll
      for (int r = 0; r < 16; ++r) sv[jt][r] = fexp2(sv[jt][r] - mrun);
    float sm[16];
#pragma unroll
    for (int r = 0; r < 16; ++r)
      sm[r] = (sv[0][r] + sv[1][r]) + (sv[2][r] + sv[3][r]);
#pragma unroll
    for (int s2 = 8; s2 > 0; s2 >>= 1)
#pragma unroll
      for (int r = 0; r < s2; ++r) sm[r] += sm[r + s2];
    lrun += sm[0] + __shfl_xor(sm[0], 32);

    // ---- P (C-layout, q=lane) -> bf16 B-frags: pack + 8-shfl half-wave exchange ----
    // word w[jt][2*rr+c2] covers j = jt*32 + 8*rr + 4*hi + 2*c2 + {0,1}
    u32 w[4][8];
#pragma unroll
    for (int jt = 0; jt < 4; ++jt)
#pragma unroll
      for (int i = 0; i < 8; ++i) w[jt][i] = pack2(sv[jt][2 * i], sv[jt][2 * i + 1]);
    bf16x8 pafr[8];  // B-frag kc: col q=l31, k-local i -> j = kc*16 + hi*8 + i
#pragma unroll
    for (int kc = 0; kc < 8; ++kc) {
      const int c = kc & 1, jt = kc >> 1;
      // pre-select what the partner half needs, single exchange serves both halves
      const u32 z1 = hi ? w[jt][4 * c + 0] : w[jt][4 * c + 2];
      const u32 z2 = hi ? w[jt][4 * c + 1] : w[jt][4 * c + 3];
      const u32 r1 = __shfl_xor(z1, 32);
      const u32 r2 = __shfl_xor(z2, 32);
      u32x4 pv;
      pv[0] = hi ? r1 : w[jt][4 * c + 0];
      pv[1] = hi ? r2 : w[jt][4 * c + 1];
      pv[2] = hi ? w[jt][4 * c + 2] : r1;
      pv[3] = hi ? w[jt][4 * c + 3] : r2;
      pafr[kc] = __builtin_bit_cast(bf16x8, pv);
    }

    // O^T += V^T * P : A = Vt rows (m=d), B = P (n=q); j-dim = 128 (8 kc granule pairs)
    __builtin_amdgcn_s_setprio(1);
#pragma unroll
    for (int dt = 0; dt < 2; ++dt) {
      const int d = dt * 32 + l31;
      const int key = (d ^ (d >> 3)) & 7;
#pragma unroll
      for (int kc = 0; kc < 8; ++kc) {
        bf16x8 vf = *(const bf16x8*)&vt[d * 128 + (((2 * kc + hi) ^ key) << 3)];
        o[dt] = __builtin_amdgcn_mfma_f32_32x32x16_bf16(vf, pafr[kc], o[dt], 0, 0, 0);
      }
    }
    __builtin_amdgcn_s_setprio(0);

    __syncthreads();
    cur ^= 1;
  }

  // epilogue: y = O/l ; xsa: y -= (y . Vn) Vn ; store (B,N,C) bf16
  // V rows read from V^T columns: VtP[d*2048 + qrow] (coalesced across lanes).
  const float linv = 1.f / lrun;
  const float vni = vninv[bh * 2048 + qrow];
  const float cvn = vni * vni;
  const bf16* vq = VtP + qrow;
  float yv[2][16], vvf[2][16];
  float t = 0.f;
#pragma unroll
  for (int dt = 0; dt < 2; ++dt)
#pragma unroll
    for (int rr = 0; rr < 4; ++rr) {
#pragma unroll
      for (int e = 0; e < 4; ++e) {
        const int r = rr * 4 + e;  // d = e + 8*rr + 4*hi + 32*dt
        const int d = e + 8 * rr + 4 * hi + 32 * dt;
        const float y = o[dt][r] * linv;
        const float vx = (float)vq[d * 2048];
        yv[dt][r] = y; vvf[dt][r] = vx;
        t += y * vx;
      }
    }
  t += __shfl_xor(t, 32);
  const float coef = t * cvn;
  bf16* yp = Yb + ((long)b * 2048 + qrow) * 1024 + h * 64;
#pragma unroll
  for (int dt = 0; dt < 2; ++dt)
#pragma unroll
    for (int rr = 0; rr < 4; ++rr) {
      bf16x4 y4;
#pragma unroll
      for (int e = 0; e < 4; ++e) {
        const int r = rr * 4 + e;
        y4[e] = (bf16)(yv[dt][r] - coef * vvf[dt][r]);
      }
      *(bf16x4*)&yp[dt * 32 + rr * 8 + hi * 4] = y4;
    }
}

// ---------------- launch ----------------
extern "C" void kernel_launch(void* const* d_in, const int* in_sizes, int n_in,
                              void* d_out, int out_size, void* d_ws, size_t ws_size,
                              hipStream_t stream) {
  (void)in_sizes; (void)n_in; (void)out_size; (void)ws_size;
  const float* x = (const float*)d_in[0];
  const float* w_qkv = (const float*)d_in[1];
  const float* w_proj = (const float*)d_in[2];
  float* out = (float*)d_out;
  char* ws = (char*)d_ws;

  bf16* xb     = (bf16*)(ws);              //  8,388,608  x as bf16
  bf16* wqkvb  = (bf16*)(ws + 8388608);    //  6,291,456
  bf16* wprojb = (bf16*)(ws + 14680064);   //  2,097,152
  bf16* Qb     = (bf16*)(ws + 16777216);   //  8,388,608  (B,H,N,D) rms-normed * 0.125*log2e
  bf16* Kb     = (bf16*)(ws + 25165824);   //  8,388,608  (B,H,N,D) rms-normed
  bf16* VtG    = (bf16*)(ws + 33554432);   //  8,388,608  (B,H,D,N) V transposed
  float* vninv = (float*)(ws + 41943040);  //    524,288  1/max(||v||,1e-12)
  bf16* Yb     = (bf16*)(ws + 42467328);   //  8,388,608  (B,N,C) post-xsa

  cvt3_kernel<<<4096, 256, 0, stream>>>(x, w_qkv, w_proj, xb, wqkvb, wprojb);

  gemm_bt<1><<<dim3(24, 32), 256, 0, stream>>>(xb, wqkvb, nullptr, 3072,
                                               Qb, Kb, VtG, vninv);
  attn_kernel<<<512, 256, 0, stream>>>(Qb, Kb, VtG, vninv, Yb);
  gemm_bt<0><<<dim3(8, 32), 256, 0, stream>>>(Yb, wprojb, out, 1024,
                                              nullptr, nullptr, nullptr, nullptr);
}